// Round 2
// baseline (4261.469 us; speedup 1.0000x reference)
//
#include <hip/hip_runtime.h>
#include <hip/hip_bf16.h>

#define N_NODES     65536
#define N_EDGES     524288
#define N_GRAPHS    512
#define G_NODES_N   10000
#define NUM_DIS     2000
#define IN_DIM      128
#define HID         256
#define D_FEAT      512

// ---------------------------------------------------------------------------
// 1. Fused projection table: proj[r] = (r<=2000 ? d_feat_tab[r]@Wd : c_feat_tab[r]@Wc)
// ---------------------------------------------------------------------------
__global__ __launch_bounds__(128) void proj_kernel(
    const float* __restrict__ dtab, const float* __restrict__ ctab,
    const float* __restrict__ Wd,   const float* __restrict__ Wc,
    float* __restrict__ proj)
{
    __shared__ float rows[8][D_FEAT];
    const int r0 = blockIdx.x * 8;
    const int j  = threadIdx.x;              // 0..127 output dim
    #pragma unroll
    for (int r = 0; r < 8; ++r) {
        const int row = r0 + r;
        const float* tab = (row <= NUM_DIS) ? dtab : ctab;
        ((float4*)rows[r])[j] = ((const float4*)(tab + (size_t)row * D_FEAT))[j];
    }
    __syncthreads();
    float acc[8] = {0.f,0.f,0.f,0.f,0.f,0.f,0.f,0.f};
    for (int k = 0; k < D_FEAT; ++k) {
        const float wd = Wd[k * IN_DIM + j];
        const float wc = Wc[k * IN_DIM + j];
        #pragma unroll
        for (int r = 0; r < 8; ++r) {
            const float w = ((r0 + r) <= NUM_DIS) ? wd : wc;
            acc[r] = fmaf(rows[r][k], w, acc[r]);
        }
    }
    #pragma unroll
    for (int r = 0; r < 8; ++r)
        proj[(size_t)(r0 + r) * IN_DIM + j] = acc[r];
}

// ---------------------------------------------------------------------------
// 2. x = concat(z_table[z], proj[node_id])   [N_NODES, 256]
// ---------------------------------------------------------------------------
__global__ __launch_bounds__(256) void build_x_kernel(
    const int* __restrict__ z, const int* __restrict__ node_id,
    const float* __restrict__ z_table, const float* __restrict__ proj,
    float* __restrict__ X)
{
    const int t = blockIdx.x * 256 + threadIdx.x;   // < N_NODES*64
    const int node = t >> 6;
    const int q    = t & 63;                        // float4 index within row
    float4 v;
    if (q < 32) v = ((const float4*)(z_table + (size_t)z[node]       * IN_DIM))[q];
    else        v = ((const float4*)(proj    + (size_t)node_id[node] * IN_DIM))[q - 32];
    ((float4*)(X + (size_t)node * HID))[q] = v;
}

// ---------------------------------------------------------------------------
// 3. Edge aggregation: AGG[dst] += F[src]   (fp32 atomics, 64 lanes per edge)
// ---------------------------------------------------------------------------
__global__ __launch_bounds__(256) void edge_agg_kernel(
    const int* __restrict__ src, const int* __restrict__ dst,
    const float* __restrict__ F, float* __restrict__ AGG)
{
    const int t = blockIdx.x * 256 + threadIdx.x;   // < N_EDGES*64
    const int e = t >> 6;
    const int q = t & 63;
    const int s = src[e];
    const int d = dst[e];
    const float4 v = ((const float4*)(F + (size_t)s * HID))[q];
    float* p = AGG + (size_t)d * HID + q * 4;
    atomicAdd(p + 0, v.x);
    atomicAdd(p + 1, v.y);
    atomicAdd(p + 2, v.z);
    atomicAdd(p + 3, v.w);
}

__global__ __launch_bounds__(256) void deg_kernel(
    const int* __restrict__ dst, float* __restrict__ deg)
{
    const int e = blockIdx.x * 256 + threadIdx.x;
    if (e < N_EDGES) atomicAdd(&deg[dst[e]], 1.0f);
}

// ---------------------------------------------------------------------------
// 4. GEMM: C = act( (A [+ Aadd]) [* 1/max(deg,1) rowwise] @ W + bias )  [+= C]
//    M x 256 @ 256 x 256, BM=BN=64, BK=16, 256 threads, 4x4 per thread.
// ---------------------------------------------------------------------------
__global__ __launch_bounds__(256) void gemm_kernel(
    const float* __restrict__ A, const float* __restrict__ Aadd,
    const float* __restrict__ deg, const float* __restrict__ W,
    const float* __restrict__ bias, float* __restrict__ C,
    const int relu, const int acc)
{
    __shared__ float As[16][68];   // [k][m], stride 68 keeps float4 alignment
    __shared__ float Bs[16][68];   // [k][n]
    const int bm  = blockIdx.x * 64;
    const int bn  = blockIdx.y * 64;
    const int tid = threadIdx.x;
    const int tx  = tid & 15;      // n-subtile
    const int ty  = tid >> 4;      // m-subtile
    const int ar  = tid >> 2;      // A-load row 0..63
    const int akq = tid & 3;       // A-load k-quad
    const int kr  = tid >> 4;      // B-load k row 0..15
    const int nq  = tid & 15;      // B-load n-quad

    float accv[4][4] = {{0.f}};

    for (int k0 = 0; k0 < HID; k0 += 16) {
        float4 av = *(const float4*)(A + (size_t)(bm + ar) * HID + k0 + akq * 4);
        if (Aadd) {
            const float4 v2 = *(const float4*)(Aadd + (size_t)(bm + ar) * HID + k0 + akq * 4);
            av.x += v2.x; av.y += v2.y; av.z += v2.z; av.w += v2.w;
        }
        if (deg) {
            const float rs = 1.0f / fmaxf(deg[bm + ar], 1.0f);
            av.x *= rs; av.y *= rs; av.z *= rs; av.w *= rs;
        }
        As[akq * 4 + 0][ar] = av.x;
        As[akq * 4 + 1][ar] = av.y;
        As[akq * 4 + 2][ar] = av.z;
        As[akq * 4 + 3][ar] = av.w;
        const float4 bv = *(const float4*)(W + (size_t)(k0 + kr) * HID + bn + nq * 4);
        *(float4*)&Bs[kr][nq * 4] = bv;
        __syncthreads();
        #pragma unroll
        for (int kk = 0; kk < 16; ++kk) {
            const float4 a = *(const float4*)&As[kk][ty * 4];
            const float4 b = *(const float4*)&Bs[kk][tx * 4];
            accv[0][0] = fmaf(a.x, b.x, accv[0][0]);
            accv[0][1] = fmaf(a.x, b.y, accv[0][1]);
            accv[0][2] = fmaf(a.x, b.z, accv[0][2]);
            accv[0][3] = fmaf(a.x, b.w, accv[0][3]);
            accv[1][0] = fmaf(a.y, b.x, accv[1][0]);
            accv[1][1] = fmaf(a.y, b.y, accv[1][1]);
            accv[1][2] = fmaf(a.y, b.z, accv[1][2]);
            accv[1][3] = fmaf(a.y, b.w, accv[1][3]);
            accv[2][0] = fmaf(a.z, b.x, accv[2][0]);
            accv[2][1] = fmaf(a.z, b.y, accv[2][1]);
            accv[2][2] = fmaf(a.z, b.z, accv[2][2]);
            accv[2][3] = fmaf(a.z, b.w, accv[2][3]);
            accv[3][0] = fmaf(a.w, b.x, accv[3][0]);
            accv[3][1] = fmaf(a.w, b.y, accv[3][1]);
            accv[3][2] = fmaf(a.w, b.z, accv[3][2]);
            accv[3][3] = fmaf(a.w, b.w, accv[3][3]);
        }
        __syncthreads();
    }

    #pragma unroll
    for (int i = 0; i < 4; ++i) {
        const int m = bm + ty * 4 + i;
        float* cp = C + (size_t)m * HID + bn + tx * 4;
        float4 v = make_float4(accv[i][0], accv[i][1], accv[i][2], accv[i][3]);
        if (bias) {
            const float4 bb = *(const float4*)(bias + bn + tx * 4);
            v.x += bb.x; v.y += bb.y; v.z += bb.z; v.w += bb.w;
        }
        if (acc) {
            const float4 o = *(const float4*)cp;
            v.x += o.x; v.y += o.y; v.z += o.z; v.w += o.w;
        }
        if (relu) {
            v.x = fmaxf(v.x, 0.f); v.y = fmaxf(v.y, 0.f);
            v.z = fmaxf(v.z, 0.f); v.w = fmaxf(v.w, 0.f);
        }
        *(float4*)cp = v;
    }
}

// ---------------------------------------------------------------------------
// 5. Per-graph max pool (graph_ids sorted -> contiguous ranges via bin search)
// ---------------------------------------------------------------------------
__global__ __launch_bounds__(256) void pool_kernel(
    const float* __restrict__ H2, const int* __restrict__ gid,
    float* __restrict__ G)
{
    const int g = blockIdx.x;     // 0..511
    const int j = threadIdx.x;    // 0..255
    int lo = 0, hi = N_NODES;
    while (lo < hi) { const int mid = (lo + hi) >> 1; if (gid[mid] < g) lo = mid + 1; else hi = mid; }
    const int start = lo;
    hi = N_NODES;
    while (lo < hi) { const int mid = (lo + hi) >> 1; if (gid[mid] < g + 1) lo = mid + 1; else hi = mid; }
    const int end = lo;
    float m = -INFINITY;
    for (int i = start; i < end; ++i)
        m = fmaxf(m, H2[(size_t)i * HID + j]);
    G[g * HID + j] = (m == -INFINITY) ? 0.0f : m;
}

// ---------------------------------------------------------------------------
// 6. Head: out[g] = relu(G[g] @ lin1 + b1) @ lin2 + b2
// ---------------------------------------------------------------------------
__global__ __launch_bounds__(256) void head_kernel(
    const float* __restrict__ G, const float* __restrict__ W1,
    const float* __restrict__ b1, const float* __restrict__ W2,
    const float* __restrict__ b2, float* __restrict__ out)
{
    const int g = blockIdx.x;
    const int j = threadIdx.x;    // 0..255
    __shared__ float row[HID];
    __shared__ float red[HID];
    row[j] = G[g * HID + j];
    __syncthreads();
    float acc = b1[j];
    for (int k = 0; k < HID; ++k)
        acc = fmaf(row[k], W1[k * HID + j], acc);
    acc = fmaxf(acc, 0.f);
    red[j] = acc * W2[j];
    __syncthreads();
    for (int s = 128; s > 0; s >>= 1) {
        if (j < s) red[j] += red[j + s];
        __syncthreads();
    }
    if (j == 0) out[g] = red[0] + b2[0];
}

// ---------------------------------------------------------------------------
extern "C" void kernel_launch(void* const* d_in, const int* in_sizes, int n_in,
                              void* d_out, int out_size, void* d_ws, size_t ws_size,
                              hipStream_t stream)
{
    const int*   z         = (const int*)d_in[0];
    const int*   node_id   = (const int*)d_in[1];
    const int*   src       = (const int*)d_in[2];
    const int*   dst       = (const int*)d_in[3];
    const int*   graph_ids = (const int*)d_in[4];
    const float* z_table   = (const float*)d_in[5];
    const float* d_feat    = (const float*)d_in[6];
    const float* c_feat    = (const float*)d_in[7];
    const float* Wd        = (const float*)d_in[8];
    const float* Wc        = (const float*)d_in[9];
    const float* gin_W1    = (const float*)d_in[10];
    const float* gin_b1    = (const float*)d_in[11];
    const float* gin_W2    = (const float*)d_in[12];
    const float* gin_b2    = (const float*)d_in[13];
    const float* sage_Wself  = (const float*)d_in[14];
    const float* sage_Wneigh = (const float*)d_in[15];
    const float* sage_b    = (const float*)d_in[16];
    const float* lin1_W    = (const float*)d_in[17];
    const float* lin1_b    = (const float*)d_in[18];
    const float* lin2_W    = (const float*)d_in[19];
    const float* lin2_b    = (const float*)d_in[20];
    float* out = (float*)d_out;

    // ---- workspace carve-up: only 3 NH-sized fp32 buffers ever live ----
    // buf0: X  -> (dead after GEMM1) -> H   (GIN output)
    // buf1: AGG (zeroed + reused for both aggregations)
    // buf2: H1 -> (dead after GEMM2) -> H2  (SAGE output)
    // Total: 3*64MB + 5.1MB + 0.4MB ~= 198 MB
    const size_t NH = (size_t)N_NODES * HID;        // 16,777,216
    float* ws   = (float*)d_ws;
    float* buf0 = ws;
    float* AGG  = ws + NH;
    float* buf2 = ws + 2 * NH;
    float* proj = ws + 3 * NH;                       // 10000*128
    float* deg  = proj + (size_t)G_NODES_N * IN_DIM; // 65536
    float* G    = deg + N_NODES;                     // 512*256

    float* X  = buf0;
    float* H1 = buf2;
    float* H  = buf0;   // reuse after X dead
    float* H2 = buf2;   // reuse after H1 dead

    // ---- zero accumulators ----
    hipMemsetAsync(AGG, 0, NH * sizeof(float), stream);
    hipMemsetAsync(deg, 0, N_NODES * sizeof(float), stream);

    // ---- 1. projection table ----
    proj_kernel<<<G_NODES_N / 8, 128, 0, stream>>>(d_feat, c_feat, Wd, Wc, proj);

    // ---- 2. build x ----
    build_x_kernel<<<(N_NODES * 64) / 256, 256, 0, stream>>>(z, node_id, z_table, proj, X);

    // ---- 3. GIN sum aggregation + degree ----
    edge_agg_kernel<<<(N_EDGES * 64) / 256, 256, 0, stream>>>(src, dst, X, AGG);
    deg_kernel<<<N_EDGES / 256, 256, 0, stream>>>(dst, deg);

    // ---- 4. GIN MLP: H1 = relu((X+AGG)@W1 + b1); H = H1@W2 + b2 ----
    dim3 ggrid(N_NODES / 64, HID / 64);
    gemm_kernel<<<ggrid, 256, 0, stream>>>(X, AGG, nullptr, gin_W1, gin_b1, H1, 1, 0);
    gemm_kernel<<<ggrid, 256, 0, stream>>>(H1, nullptr, nullptr, gin_W2, gin_b2, H, 0, 0);

    // ---- 5. SAGE mean aggregation (reuse AGG) ----
    hipMemsetAsync(AGG, 0, NH * sizeof(float), stream);
    edge_agg_kernel<<<(N_EDGES * 64) / 256, 256, 0, stream>>>(src, dst, H, AGG);

    // ---- 6. SAGE: H2 = H@Wself + sage_b; H2 += (AGG/deg)@Wneigh ----
    gemm_kernel<<<ggrid, 256, 0, stream>>>(H, nullptr, nullptr, sage_Wself, sage_b, H2, 0, 0);
    gemm_kernel<<<ggrid, 256, 0, stream>>>(AGG, nullptr, deg, sage_Wneigh, nullptr, H2, 0, 1);

    // ---- 7. per-graph max pool ----
    pool_kernel<<<N_GRAPHS, 256, 0, stream>>>(H2, graph_ids, G);

    // ---- 8. head ----
    head_kernel<<<N_GRAPHS, 256, 0, stream>>>(G, lin1_W, lin1_b, lin2_W, lin2_b, out);
}

// Round 3
// 985.032 us; speedup vs baseline: 4.3262x; 4.3262x over previous
//
#include <hip/hip_runtime.h>
#include <hip/hip_bf16.h>

#define N_NODES     65536
#define N_EDGES     524288
#define N_GRAPHS    512
#define G_NODES_N   10000
#define NUM_DIS     2000
#define IN_DIM      128
#define HID         256
#define D_FEAT      512

// ---------------------------------------------------------------------------
// 1. Fused projection table: proj[r] = (r<=2000 ? d_feat_tab[r]@Wd : c_feat_tab[r]@Wc)
// ---------------------------------------------------------------------------
__global__ __launch_bounds__(128) void proj_kernel(
    const float* __restrict__ dtab, const float* __restrict__ ctab,
    const float* __restrict__ Wd,   const float* __restrict__ Wc,
    float* __restrict__ proj)
{
    __shared__ float rows[8][D_FEAT];
    const int r0 = blockIdx.x * 8;
    const int j  = threadIdx.x;              // 0..127 output dim
    #pragma unroll
    for (int r = 0; r < 8; ++r) {
        const int row = r0 + r;
        const float* tab = (row <= NUM_DIS) ? dtab : ctab;
        ((float4*)rows[r])[j] = ((const float4*)(tab + (size_t)row * D_FEAT))[j];
    }
    __syncthreads();
    float acc[8] = {0.f,0.f,0.f,0.f,0.f,0.f,0.f,0.f};
    for (int k = 0; k < D_FEAT; ++k) {
        const float wd = Wd[k * IN_DIM + j];
        const float wc = Wc[k * IN_DIM + j];
        #pragma unroll
        for (int r = 0; r < 8; ++r) {
            const float w = ((r0 + r) <= NUM_DIS) ? wd : wc;
            acc[r] = fmaf(rows[r][k], w, acc[r]);
        }
    }
    #pragma unroll
    for (int r = 0; r < 8; ++r)
        proj[(size_t)(r0 + r) * IN_DIM + j] = acc[r];
}

// ---------------------------------------------------------------------------
// 2. x = concat(z_table[z], proj[node_id])   [N_NODES, 256]
// ---------------------------------------------------------------------------
__global__ __launch_bounds__(256) void build_x_kernel(
    const int* __restrict__ z, const int* __restrict__ node_id,
    const float* __restrict__ z_table, const float* __restrict__ proj,
    float* __restrict__ X)
{
    const int t = blockIdx.x * 256 + threadIdx.x;   // < N_NODES*64
    const int node = t >> 6;
    const int q    = t & 63;                        // float4 index within row
    float4 v;
    if (q < 32) v = ((const float4*)(z_table + (size_t)z[node]       * IN_DIM))[q];
    else        v = ((const float4*)(proj    + (size_t)node_id[node] * IN_DIM))[q - 32];
    ((float4*)(X + (size_t)node * HID))[q] = v;
}

// ---------------------------------------------------------------------------
// 3. CSR build: histogram -> single-block scan -> scatter (src ids per dst)
// ---------------------------------------------------------------------------
__global__ __launch_bounds__(256) void hist_kernel(
    const int* __restrict__ dst, int* __restrict__ cnt)
{
    const int e = blockIdx.x * 256 + threadIdx.x;
    if (e < N_EDGES) atomicAdd(&cnt[dst[e]], 1);
}

// Exclusive scan of 65536 ints with ONE block of 256 threads (256 per thread).
__global__ __launch_bounds__(256) void scan_kernel(
    const int* __restrict__ cnt, int* __restrict__ row_ptr)
{
    __shared__ int bufA[256], bufB[256];
    const int t = threadIdx.x;
    const int base = t * 256;
    int s = 0;
    for (int i = 0; i < 256; ++i) s += cnt[base + i];
    bufA[t] = s;
    __syncthreads();
    int* in = bufA; int* out = bufB;
    for (int off = 1; off < 256; off <<= 1) {
        out[t] = in[t] + ((t >= off) ? in[t - off] : 0);
        __syncthreads();
        int* tmp = in; in = out; out = tmp;
    }
    int run = in[t] - s;   // exclusive prefix of this thread's chunk
    for (int i = 0; i < 256; ++i) {
        row_ptr[base + i] = run;
        run += cnt[base + i];
    }
    if (t == 255) row_ptr[N_NODES] = run;
}

__global__ __launch_bounds__(256) void scatter_kernel(
    const int* __restrict__ src, const int* __restrict__ dst,
    const int* __restrict__ row_ptr, int* __restrict__ fill,
    int* __restrict__ col)
{
    const int e = blockIdx.x * 256 + threadIdx.x;
    if (e < N_EDGES) {
        const int d = dst[e];
        const int pos = atomicAdd(&fill[d], 1);
        col[row_ptr[d] + pos] = src[e];
    }
}

// ---------------------------------------------------------------------------
// 4. CSR gather-aggregation: one wave per dst node, no atomics.
//    OUT[d] = [Self[d] +] sum_{s in N(d)} F[s]   [ / max(deg,1) ]
// ---------------------------------------------------------------------------
__global__ __launch_bounds__(256) void csr_agg_kernel(
    const int* __restrict__ row_ptr, const int* __restrict__ col,
    const float* __restrict__ F, const float* __restrict__ Self,
    float* __restrict__ OUT, const int mean_mode)
{
    const int t = blockIdx.x * 256 + threadIdx.x;   // < N_NODES*64
    const int d = t >> 6;
    const int q = t & 63;
    const int beg = row_ptr[d];
    const int end = row_ptr[d + 1];
    float4 acc = make_float4(0.f, 0.f, 0.f, 0.f);
    if (Self) acc = ((const float4*)(Self + (size_t)d * HID))[q];
    for (int e = beg; e < end; ++e) {
        const int s = col[e];
        const float4 v = ((const float4*)(F + (size_t)s * HID))[q];
        acc.x += v.x; acc.y += v.y; acc.z += v.z; acc.w += v.w;
    }
    if (mean_mode) {
        const float rs = 1.0f / fmaxf((float)(end - beg), 1.0f);
        acc.x *= rs; acc.y *= rs; acc.z *= rs; acc.w *= rs;
    }
    ((float4*)(OUT + (size_t)d * HID))[q] = acc;
}

// ---------------------------------------------------------------------------
// 5. GEMM: C = act( A @ W + bias ) [+= C]
//    M x 256 @ 256 x 256, BM=BN=64, BK=16, 256 threads, 4x4 per thread.
// ---------------------------------------------------------------------------
__global__ __launch_bounds__(256) void gemm_kernel(
    const float* __restrict__ A, const float* __restrict__ W,
    const float* __restrict__ bias, float* __restrict__ C,
    const int relu, const int acc)
{
    __shared__ float As[16][68];   // [k][m], stride 68 keeps float4 alignment
    __shared__ float Bs[16][68];   // [k][n]
    const int bm  = blockIdx.x * 64;
    const int bn  = blockIdx.y * 64;
    const int tid = threadIdx.x;
    const int tx  = tid & 15;      // n-subtile
    const int ty  = tid >> 4;      // m-subtile
    const int ar  = tid >> 2;      // A-load row 0..63
    const int akq = tid & 3;       // A-load k-quad
    const int kr  = tid >> 4;      // B-load k row 0..15
    const int nq  = tid & 15;      // B-load n-quad

    float accv[4][4] = {{0.f}};

    for (int k0 = 0; k0 < HID; k0 += 16) {
        const float4 av = *(const float4*)(A + (size_t)(bm + ar) * HID + k0 + akq * 4);
        As[akq * 4 + 0][ar] = av.x;
        As[akq * 4 + 1][ar] = av.y;
        As[akq * 4 + 2][ar] = av.z;
        As[akq * 4 + 3][ar] = av.w;
        const float4 bv = *(const float4*)(W + (size_t)(k0 + kr) * HID + bn + nq * 4);
        *(float4*)&Bs[kr][nq * 4] = bv;
        __syncthreads();
        #pragma unroll
        for (int kk = 0; kk < 16; ++kk) {
            const float4 a = *(const float4*)&As[kk][ty * 4];
            const float4 b = *(const float4*)&Bs[kk][tx * 4];
            accv[0][0] = fmaf(a.x, b.x, accv[0][0]);
            accv[0][1] = fmaf(a.x, b.y, accv[0][1]);
            accv[0][2] = fmaf(a.x, b.z, accv[0][2]);
            accv[0][3] = fmaf(a.x, b.w, accv[0][3]);
            accv[1][0] = fmaf(a.y, b.x, accv[1][0]);
            accv[1][1] = fmaf(a.y, b.y, accv[1][1]);
            accv[1][2] = fmaf(a.y, b.z, accv[1][2]);
            accv[1][3] = fmaf(a.y, b.w, accv[1][3]);
            accv[2][0] = fmaf(a.z, b.x, accv[2][0]);
            accv[2][1] = fmaf(a.z, b.y, accv[2][1]);
            accv[2][2] = fmaf(a.z, b.z, accv[2][2]);
            accv[2][3] = fmaf(a.z, b.w, accv[2][3]);
            accv[3][0] = fmaf(a.w, b.x, accv[3][0]);
            accv[3][1] = fmaf(a.w, b.y, accv[3][1]);
            accv[3][2] = fmaf(a.w, b.z, accv[3][2]);
            accv[3][3] = fmaf(a.w, b.w, accv[3][3]);
        }
        __syncthreads();
    }

    #pragma unroll
    for (int i = 0; i < 4; ++i) {
        const int m = bm + ty * 4 + i;
        float* cp = C + (size_t)m * HID + bn + tx * 4;
        float4 v = make_float4(accv[i][0], accv[i][1], accv[i][2], accv[i][3]);
        if (bias) {
            const float4 bb = *(const float4*)(bias + bn + tx * 4);
            v.x += bb.x; v.y += bb.y; v.z += bb.z; v.w += bb.w;
        }
        if (acc) {
            const float4 o = *(const float4*)cp;
            v.x += o.x; v.y += o.y; v.z += o.z; v.w += o.w;
        }
        if (relu) {
            v.x = fmaxf(v.x, 0.f); v.y = fmaxf(v.y, 0.f);
            v.z = fmaxf(v.z, 0.f); v.w = fmaxf(v.w, 0.f);
        }
        *(float4*)cp = v;
    }
}

// ---------------------------------------------------------------------------
// 6. Per-graph max pool (graph_ids sorted -> contiguous ranges via bin search)
// ---------------------------------------------------------------------------
__global__ __launch_bounds__(256) void pool_kernel(
    const float* __restrict__ H2, const int* __restrict__ gid,
    float* __restrict__ G)
{
    const int g = blockIdx.x;     // 0..511
    const int j = threadIdx.x;    // 0..255
    int lo = 0, hi = N_NODES;
    while (lo < hi) { const int mid = (lo + hi) >> 1; if (gid[mid] < g) lo = mid + 1; else hi = mid; }
    const int start = lo;
    hi = N_NODES;
    while (lo < hi) { const int mid = (lo + hi) >> 1; if (gid[mid] < g + 1) lo = mid + 1; else hi = mid; }
    const int end = lo;
    float m = -INFINITY;
    for (int i = start; i < end; ++i)
        m = fmaxf(m, H2[(size_t)i * HID + j]);
    G[g * HID + j] = (m == -INFINITY) ? 0.0f : m;
}

// ---------------------------------------------------------------------------
// 7. Head: out[g] = relu(G[g] @ lin1 + b1) @ lin2 + b2
// ---------------------------------------------------------------------------
__global__ __launch_bounds__(256) void head_kernel(
    const float* __restrict__ G, const float* __restrict__ W1,
    const float* __restrict__ b1, const float* __restrict__ W2,
    const float* __restrict__ b2, float* __restrict__ out)
{
    const int g = blockIdx.x;
    const int j = threadIdx.x;    // 0..255
    __shared__ float row[HID];
    __shared__ float red[HID];
    row[j] = G[g * HID + j];
    __syncthreads();
    float acc = b1[j];
    for (int k = 0; k < HID; ++k)
        acc = fmaf(row[k], W1[k * HID + j], acc);
    acc = fmaxf(acc, 0.f);
    red[j] = acc * W2[j];
    __syncthreads();
    for (int s = 128; s > 0; s >>= 1) {
        if (j < s) red[j] += red[j + s];
        __syncthreads();
    }
    if (j == 0) out[g] = red[0] + b2[0];
}

// ---------------------------------------------------------------------------
extern "C" void kernel_launch(void* const* d_in, const int* in_sizes, int n_in,
                              void* d_out, int out_size, void* d_ws, size_t ws_size,
                              hipStream_t stream)
{
    const int*   z         = (const int*)d_in[0];
    const int*   node_id   = (const int*)d_in[1];
    const int*   src       = (const int*)d_in[2];
    const int*   dst       = (const int*)d_in[3];
    const int*   graph_ids = (const int*)d_in[4];
    const float* z_table   = (const float*)d_in[5];
    const float* d_feat    = (const float*)d_in[6];
    const float* c_feat    = (const float*)d_in[7];
    const float* Wd        = (const float*)d_in[8];
    const float* Wc        = (const float*)d_in[9];
    const float* gin_W1    = (const float*)d_in[10];
    const float* gin_b1    = (const float*)d_in[11];
    const float* gin_W2    = (const float*)d_in[12];
    const float* gin_b2    = (const float*)d_in[13];
    const float* sage_Wself  = (const float*)d_in[14];
    const float* sage_Wneigh = (const float*)d_in[15];
    const float* sage_b    = (const float*)d_in[16];
    const float* lin1_W    = (const float*)d_in[17];
    const float* lin1_b    = (const float*)d_in[18];
    const float* lin2_W    = (const float*)d_in[19];
    const float* lin2_b    = (const float*)d_in[20];
    float* out = (float*)d_out;

    // ---- workspace carve-up: 3 NH-sized fp32 buffers + proj + CSR ----
    // buf0: X  -> (dead after GEMM1) -> H   (GIN output)
    // buf1: AGG (both aggregations)
    // buf2: H1 -> (dead after GEMM2) -> H2  (SAGE output)
    const size_t NH = (size_t)N_NODES * HID;        // 16,777,216
    float* ws   = (float*)d_ws;
    float* buf0 = ws;
    float* AGG  = ws + NH;
    float* buf2 = ws + 2 * NH;
    float* proj = ws + 3 * NH;                       // 10000*128
    float* G    = proj + (size_t)G_NODES_N * IN_DIM; // 512*256
    int* row_ptr = (int*)(G + (size_t)N_GRAPHS * HID);   // 65537
    int* cnt     = row_ptr + (N_NODES + 2);              // 65536 (hist, then fill)
    int* col     = cnt + N_NODES;                        // 524288

    float* X  = buf0;
    float* H1 = buf2;
    float* H  = buf0;   // reuse after X dead
    float* H2 = buf2;   // reuse after H1 dead

    // ---- CSR build (shared by both aggregations) ----
    hipMemsetAsync(cnt, 0, N_NODES * sizeof(int), stream);
    hist_kernel<<<N_EDGES / 256, 256, 0, stream>>>(dst, cnt);
    scan_kernel<<<1, 256, 0, stream>>>(cnt, row_ptr);
    hipMemsetAsync(cnt, 0, N_NODES * sizeof(int), stream);
    scatter_kernel<<<N_EDGES / 256, 256, 0, stream>>>(src, dst, row_ptr, cnt, col);

    // ---- 1. projection table ----
    proj_kernel<<<G_NODES_N / 8, 128, 0, stream>>>(d_feat, c_feat, Wd, Wc, proj);

    // ---- 2. build x ----
    build_x_kernel<<<(N_NODES * 64) / 256, 256, 0, stream>>>(z, node_id, z_table, proj, X);

    // ---- 3. GIN aggregation: AGG = X + sum_neigh(X)  (self fused) ----
    csr_agg_kernel<<<(N_NODES * 64) / 256, 256, 0, stream>>>(row_ptr, col, X, X, AGG, 0);

    // ---- 4. GIN MLP: H1 = relu(AGG@W1 + b1); H = H1@W2 + b2 ----
    dim3 ggrid(N_NODES / 64, HID / 64);
    gemm_kernel<<<ggrid, 256, 0, stream>>>(AGG, gin_W1, gin_b1, H1, 1, 0);
    gemm_kernel<<<ggrid, 256, 0, stream>>>(H1, gin_W2, gin_b2, H, 0, 0);

    // ---- 5. SAGE mean aggregation: AGG = mean_neigh(H) ----
    csr_agg_kernel<<<(N_NODES * 64) / 256, 256, 0, stream>>>(row_ptr, col, H, nullptr, AGG, 1);

    // ---- 6. SAGE: H2 = H@Wself + sage_b; H2 += AGG@Wneigh ----
    gemm_kernel<<<ggrid, 256, 0, stream>>>(H, sage_Wself, sage_b, H2, 0, 0);
    gemm_kernel<<<ggrid, 256, 0, stream>>>(AGG, sage_Wneigh, nullptr, H2, 0, 1);

    // ---- 7. per-graph max pool ----
    pool_kernel<<<N_GRAPHS, 256, 0, stream>>>(H2, graph_ids, G);

    // ---- 8. head ----
    head_kernel<<<N_GRAPHS, 256, 0, stream>>>(G, lin1_W, lin1_b, lin2_W, lin2_b, out);
}

// Round 4
// 554.239 us; speedup vs baseline: 7.6889x; 1.7773x over previous
//
#include <hip/hip_runtime.h>
#include <hip/hip_bf16.h>

#define N_NODES     65536
#define N_EDGES     524288
#define N_GRAPHS    512
#define G_NODES_N   10000
#define NUM_DIS     2000
#define IN_DIM      128
#define HID         256
#define D_FEAT      512

typedef _Float16 half8 __attribute__((ext_vector_type(8)));
typedef _Float16 half4v __attribute__((ext_vector_type(4)));
typedef float    f32x4 __attribute__((ext_vector_type(4)));

// ---------------------------------------------------------------------------
// 1. Fused projection table: proj[r] = (r<=2000 ? d_feat_tab[r]@Wd : c_feat_tab[r]@Wc)
// ---------------------------------------------------------------------------
__global__ __launch_bounds__(128) void proj_kernel(
    const float* __restrict__ dtab, const float* __restrict__ ctab,
    const float* __restrict__ Wd,   const float* __restrict__ Wc,
    float* __restrict__ proj)
{
    __shared__ float rows[8][D_FEAT];
    const int r0 = blockIdx.x * 8;
    const int j  = threadIdx.x;              // 0..127 output dim
    #pragma unroll
    for (int r = 0; r < 8; ++r) {
        const int row = r0 + r;
        const float* tab = (row <= NUM_DIS) ? dtab : ctab;
        ((float4*)rows[r])[j] = ((const float4*)(tab + (size_t)row * D_FEAT))[j];
    }
    __syncthreads();
    float acc[8] = {0.f,0.f,0.f,0.f,0.f,0.f,0.f,0.f};
    for (int k = 0; k < D_FEAT; ++k) {
        const float wd = Wd[k * IN_DIM + j];
        const float wc = Wc[k * IN_DIM + j];
        #pragma unroll
        for (int r = 0; r < 8; ++r) {
            const float w = ((r0 + r) <= NUM_DIS) ? wd : wc;
            acc[r] = fmaf(rows[r][k], w, acc[r]);
        }
    }
    #pragma unroll
    for (int r = 0; r < 8; ++r)
        proj[(size_t)(r0 + r) * IN_DIM + j] = acc[r];
}

// ---------------------------------------------------------------------------
// 2. x = concat(z_table[z], proj[node_id])  -> f16  [N_NODES, 256]
// ---------------------------------------------------------------------------
__global__ __launch_bounds__(256) void build_x_kernel(
    const int* __restrict__ z, const int* __restrict__ node_id,
    const float* __restrict__ z_table, const float* __restrict__ proj,
    _Float16* __restrict__ X)
{
    const int t = blockIdx.x * 256 + threadIdx.x;   // < N_NODES*64
    const int node = t >> 6;
    const int q    = t & 63;                        // 4-elem group within row
    float4 v;
    if (q < 32) v = ((const float4*)(z_table + (size_t)z[node]       * IN_DIM))[q];
    else        v = ((const float4*)(proj    + (size_t)node_id[node] * IN_DIM))[q - 32];
    half4v h;
    h[0] = (_Float16)v.x; h[1] = (_Float16)v.y;
    h[2] = (_Float16)v.z; h[3] = (_Float16)v.w;
    *(half4v*)(X + (size_t)node * HID + q * 4) = h;
}

// ---------------------------------------------------------------------------
// 3. Weight convert+transpose: WT[n][k] = (f16) W[k][n]
// ---------------------------------------------------------------------------
__global__ __launch_bounds__(256) void wcvt_kernel(
    const float* __restrict__ W, _Float16* __restrict__ WT)
{
    const int n = blockIdx.x;
    const int k = threadIdx.x;
    WT[n * HID + k] = (_Float16)W[k * HID + n];
}

// ---------------------------------------------------------------------------
// 4. CSR build: histogram -> single-block scan -> scatter (src ids per dst)
// ---------------------------------------------------------------------------
__global__ __launch_bounds__(256) void hist_kernel(
    const int* __restrict__ dst, int* __restrict__ cnt)
{
    const int e = blockIdx.x * 256 + threadIdx.x;
    if (e < N_EDGES) atomicAdd(&cnt[dst[e]], 1);
}

__global__ __launch_bounds__(256) void scan_kernel(
    const int* __restrict__ cnt, int* __restrict__ row_ptr)
{
    __shared__ int bufA[256], bufB[256];
    const int t = threadIdx.x;
    const int base = t * 256;
    int s = 0;
    for (int i = 0; i < 256; ++i) s += cnt[base + i];
    bufA[t] = s;
    __syncthreads();
    int* in = bufA; int* out = bufB;
    for (int off = 1; off < 256; off <<= 1) {
        out[t] = in[t] + ((t >= off) ? in[t - off] : 0);
        __syncthreads();
        int* tmp = in; in = out; out = tmp;
    }
    int run = in[t] - s;   // exclusive prefix of this thread's chunk
    for (int i = 0; i < 256; ++i) {
        row_ptr[base + i] = run;
        run += cnt[base + i];
    }
    if (t == 255) row_ptr[N_NODES] = run;
}

__global__ __launch_bounds__(256) void scatter_kernel(
    const int* __restrict__ src, const int* __restrict__ dst,
    const int* __restrict__ row_ptr, int* __restrict__ fill,
    int* __restrict__ col)
{
    const int e = blockIdx.x * 256 + threadIdx.x;
    if (e < N_EDGES) {
        const int d = dst[e];
        const int pos = atomicAdd(&fill[d], 1);
        col[row_ptr[d] + pos] = src[e];
    }
}

// ---------------------------------------------------------------------------
// 5. CSR gather-aggregation (f16 in/out, fp32 accumulate), no atomics.
//    OUT[d] = [Self[d] +] sum_{s in N(d)} F[s]   [ / max(deg,1) ]
// ---------------------------------------------------------------------------
__global__ __launch_bounds__(256) void csr_agg_kernel(
    const int* __restrict__ row_ptr, const int* __restrict__ col,
    const _Float16* __restrict__ F, const _Float16* __restrict__ Self,
    _Float16* __restrict__ OUT, const int mean_mode)
{
    const int t = blockIdx.x * 256 + threadIdx.x;   // < N_NODES*64
    const int d = t >> 6;
    const int q = t & 63;
    const int beg = row_ptr[d];
    const int end = row_ptr[d + 1];
    f32x4 acc = {0.f, 0.f, 0.f, 0.f};
    if (Self) {
        const half4v s = *(const half4v*)(Self + (size_t)d * HID + q * 4);
        acc[0] = (float)s[0]; acc[1] = (float)s[1];
        acc[2] = (float)s[2]; acc[3] = (float)s[3];
    }
    for (int e = beg; e < end; ++e) {
        const int s = col[e];
        const half4v v = *(const half4v*)(F + (size_t)s * HID + q * 4);
        acc[0] += (float)v[0]; acc[1] += (float)v[1];
        acc[2] += (float)v[2]; acc[3] += (float)v[3];
    }
    if (mean_mode) {
        const float rs = 1.0f / fmaxf((float)(end - beg), 1.0f);
        acc[0] *= rs; acc[1] *= rs; acc[2] *= rs; acc[3] *= rs;
    }
    half4v o;
    o[0] = (_Float16)acc[0]; o[1] = (_Float16)acc[1];
    o[2] = (_Float16)acc[2]; o[3] = (_Float16)acc[3];
    *(half4v*)(OUT + (size_t)d * HID + q * 4) = o;
}

// ---------------------------------------------------------------------------
// 6. MFMA f16 GEMM: C = act( [A1|A2] @ [B1;B2] + bias )
//    BM=128, BN=128, BK=32, 256 threads (4 waves), each wave 64x64.
//    A row-major f16 [M][256]; B*T is [n][k] f16 (pre-transposed weights).
//    Output: Cf (fp32) and/or Ch (f16).
// ---------------------------------------------------------------------------
__global__ __launch_bounds__(256) void mfma_gemm_kernel(
    const _Float16* __restrict__ A1, const _Float16* __restrict__ A2,
    const _Float16* __restrict__ B1T, const _Float16* __restrict__ B2T,
    const float* __restrict__ bias, float* __restrict__ Cf,
    _Float16* __restrict__ Ch, const int relu)
{
    // LDS: [row][k] with row stride 40 halves (80 B): 16B-aligned, free 2-way banking
    __shared__ _Float16 Alds[128 * 40];
    __shared__ _Float16 Blds[128 * 40];
    const int bm   = blockIdx.x * 128;
    const int bn   = blockIdx.y * 128;
    const int tid  = threadIdx.x;
    const int wave = tid >> 6, lane = tid & 63;
    const int q    = lane >> 4, l16 = lane & 15;
    const int mbase = (wave & 1) * 64, nbase = (wave >> 1) * 64;
    const int r = tid >> 1, s = tid & 1;     // staging: row 0..127, 16-half segment

    f32x4 acc[4][4] = {};
    const int nchunks = A2 ? 16 : 8;

    for (int kc = 0; kc < nchunks; ++kc) {
        const int k0 = (kc & 7) * 32;
        const _Float16* gA = ((kc < 8) ? A1 : A2) + (size_t)(bm + r) * HID + k0 + s * 16;
        const _Float16* gB = ((kc < 8) ? B1T : B2T) + (size_t)(bn + r) * HID + k0 + s * 16;
        __syncthreads();   // protect LDS from previous iteration's readers
        *(half8*)&Alds[r * 40 + s * 16]     = *(const half8*)gA;
        *(half8*)&Alds[r * 40 + s * 16 + 8] = *(const half8*)(gA + 8);
        *(half8*)&Blds[r * 40 + s * 16]     = *(const half8*)gB;
        *(half8*)&Blds[r * 40 + s * 16 + 8] = *(const half8*)(gB + 8);
        __syncthreads();
        half8 a[4], b[4];
        #pragma unroll
        for (int i = 0; i < 4; ++i)
            a[i] = *(const half8*)&Alds[(mbase + i * 16 + l16) * 40 + q * 8];
        #pragma unroll
        for (int j = 0; j < 4; ++j)
            b[j] = *(const half8*)&Blds[(nbase + j * 16 + l16) * 40 + q * 8];
        #pragma unroll
        for (int i = 0; i < 4; ++i)
            #pragma unroll
            for (int j = 0; j < 4; ++j)
                acc[i][j] = __builtin_amdgcn_mfma_f32_16x16x32_f16(a[i], b[j], acc[i][j], 0, 0, 0);
    }

    // epilogue: D row=(q*4+rr within 16-tile), col=l16
    #pragma unroll
    for (int j = 0; j < 4; ++j) {
        const int colg = bn + nbase + j * 16 + l16;
        const float bv = bias ? bias[colg] : 0.0f;
        #pragma unroll
        for (int i = 0; i < 4; ++i) {
            #pragma unroll
            for (int rr = 0; rr < 4; ++rr) {
                const int rowg = bm + mbase + i * 16 + q * 4 + rr;
                float v = acc[i][j][rr] + bv;
                if (relu) v = fmaxf(v, 0.0f);
                if (Cf) Cf[(size_t)rowg * HID + colg] = v;
                if (Ch) Ch[(size_t)rowg * HID + colg] = (_Float16)v;
            }
        }
    }
}

// ---------------------------------------------------------------------------
// 7. Per-graph max pool (graph_ids sorted -> contiguous ranges via bin search)
// ---------------------------------------------------------------------------
__global__ __launch_bounds__(256) void pool_kernel(
    const float* __restrict__ H2, const int* __restrict__ gid,
    float* __restrict__ G)
{
    const int g = blockIdx.x;     // 0..511
    const int j = threadIdx.x;    // 0..255
    int lo = 0, hi = N_NODES;
    while (lo < hi) { const int mid = (lo + hi) >> 1; if (gid[mid] < g) lo = mid + 1; else hi = mid; }
    const int start = lo;
    hi = N_NODES;
    while (lo < hi) { const int mid = (lo + hi) >> 1; if (gid[mid] < g + 1) lo = mid + 1; else hi = mid; }
    const int end = lo;
    float m = -INFINITY;
    for (int i = start; i < end; ++i)
        m = fmaxf(m, H2[(size_t)i * HID + j]);
    G[g * HID + j] = (m == -INFINITY) ? 0.0f : m;
}

// ---------------------------------------------------------------------------
// 8. Head: out[g] = relu(G[g] @ lin1 + b1) @ lin2 + b2
// ---------------------------------------------------------------------------
__global__ __launch_bounds__(256) void head_kernel(
    const float* __restrict__ G, const float* __restrict__ W1,
    const float* __restrict__ b1, const float* __restrict__ W2,
    const float* __restrict__ b2, float* __restrict__ out)
{
    const int g = blockIdx.x;
    const int j = threadIdx.x;    // 0..255
    __shared__ float row[HID];
    __shared__ float red[HID];
    row[j] = G[g * HID + j];
    __syncthreads();
    float acc = b1[j];
    for (int k = 0; k < HID; ++k)
        acc = fmaf(row[k], W1[k * HID + j], acc);
    acc = fmaxf(acc, 0.f);
    red[j] = acc * W2[j];
    __syncthreads();
    for (int s = 128; s > 0; s >>= 1) {
        if (j < s) red[j] += red[j + s];
        __syncthreads();
    }
    if (j == 0) out[g] = red[0] + b2[0];
}

// ---------------------------------------------------------------------------
extern "C" void kernel_launch(void* const* d_in, const int* in_sizes, int n_in,
                              void* d_out, int out_size, void* d_ws, size_t ws_size,
                              hipStream_t stream)
{
    const int*   z         = (const int*)d_in[0];
    const int*   node_id   = (const int*)d_in[1];
    const int*   src       = (const int*)d_in[2];
    const int*   dst       = (const int*)d_in[3];
    const int*   graph_ids = (const int*)d_in[4];
    const float* z_table   = (const float*)d_in[5];
    const float* d_feat    = (const float*)d_in[6];
    const float* c_feat    = (const float*)d_in[7];
    const float* Wd        = (const float*)d_in[8];
    const float* Wc        = (const float*)d_in[9];
    const float* gin_W1    = (const float*)d_in[10];
    const float* gin_b1    = (const float*)d_in[11];
    const float* gin_W2    = (const float*)d_in[12];
    const float* gin_b2    = (const float*)d_in[13];
    const float* sage_Wself  = (const float*)d_in[14];
    const float* sage_Wneigh = (const float*)d_in[15];
    const float* sage_b    = (const float*)d_in[16];
    const float* lin1_W    = (const float*)d_in[17];
    const float* lin1_b    = (const float*)d_in[18];
    const float* lin2_W    = (const float*)d_in[19];
    const float* lin2_b    = (const float*)d_in[20];
    float* out = (float*)d_out;

    // ---- workspace carve-up ----
    const size_t NH = (size_t)N_NODES * HID;        // 16,777,216 elements
    char* wsb = (char*)d_ws;
    _Float16* bufA = (_Float16*)wsb;                     wsb += NH * 2;  // Xh -> Hh
    _Float16* AGGh = (_Float16*)wsb;                     wsb += NH * 2;  // both aggs
    _Float16* H1h  = (_Float16*)wsb;                     wsb += NH * 2;
    float*    H2   = (float*)wsb;                        wsb += NH * 4;
    float*    proj = (float*)wsb;                        wsb += (size_t)G_NODES_N * IN_DIM * 4;
    _Float16* W1T  = (_Float16*)wsb;                     wsb += HID * HID * 2;
    _Float16* W2T  = (_Float16*)wsb;                     wsb += HID * HID * 2;
    _Float16* WsT  = (_Float16*)wsb;                     wsb += HID * HID * 2;
    _Float16* WnT  = (_Float16*)wsb;                     wsb += HID * HID * 2;
    float*    G    = (float*)wsb;                        wsb += (size_t)N_GRAPHS * HID * 4;
    int* row_ptr   = (int*)wsb;                          wsb += (N_NODES + 4) * 4;
    int* cnt       = (int*)wsb;                          wsb += N_NODES * 4;
    int* col       = (int*)wsb;                          wsb += N_EDGES * 4;

    _Float16* Xh = bufA;
    _Float16* Hh = bufA;   // reuse after X dead

    // ---- CSR build (shared by both aggregations) ----
    hipMemsetAsync(cnt, 0, N_NODES * sizeof(int), stream);
    hist_kernel<<<N_EDGES / 256, 256, 0, stream>>>(dst, cnt);
    scan_kernel<<<1, 256, 0, stream>>>(cnt, row_ptr);
    hipMemsetAsync(cnt, 0, N_NODES * sizeof(int), stream);
    scatter_kernel<<<N_EDGES / 256, 256, 0, stream>>>(src, dst, row_ptr, cnt, col);

    // ---- weights -> f16 transposed ----
    wcvt_kernel<<<HID, HID, 0, stream>>>(gin_W1, W1T);
    wcvt_kernel<<<HID, HID, 0, stream>>>(gin_W2, W2T);
    wcvt_kernel<<<HID, HID, 0, stream>>>(sage_Wself, WsT);
    wcvt_kernel<<<HID, HID, 0, stream>>>(sage_Wneigh, WnT);

    // ---- projection table + x ----
    proj_kernel<<<G_NODES_N / 8, 128, 0, stream>>>(d_feat, c_feat, Wd, Wc, proj);
    build_x_kernel<<<(N_NODES * 64) / 256, 256, 0, stream>>>(z, node_id, z_table, proj, Xh);

    // ---- GIN aggregation: AGG = X + sum_neigh(X) ----
    csr_agg_kernel<<<(N_NODES * 64) / 256, 256, 0, stream>>>(row_ptr, col, Xh, Xh, AGGh, 0);

    // ---- GIN MLP: H1 = relu(AGG@W1+b1); H = H1@W2+b2 ----
    dim3 ggrid(N_NODES / 128, HID / 128);
    mfma_gemm_kernel<<<ggrid, 256, 0, stream>>>(AGGh, nullptr, W1T, nullptr, gin_b1, nullptr, H1h, 1);
    mfma_gemm_kernel<<<ggrid, 256, 0, stream>>>(H1h, nullptr, W2T, nullptr, gin_b2, nullptr, Hh, 0);

    // ---- SAGE mean aggregation: AGG = mean_neigh(H) ----
    csr_agg_kernel<<<(N_NODES * 64) / 256, 256, 0, stream>>>(row_ptr, col, Hh, nullptr, AGGh, 1);

    // ---- SAGE fused: H2 = H@Wself + AGG@Wneigh + b  (K=512) ----
    mfma_gemm_kernel<<<ggrid, 256, 0, stream>>>(Hh, AGGh, WsT, WnT, sage_b, H2, nullptr, 0);

    // ---- per-graph max pool ----
    pool_kernel<<<N_GRAPHS, 256, 0, stream>>>(H2, graph_ids, G);

    // ---- head ----
    head_kernel<<<N_GRAPHS, 256, 0, stream>>>(G, lin1_W, lin1_b, lin2_W, lin2_b, out);
}

// Round 5
// 488.214 us; speedup vs baseline: 8.7287x; 1.1352x over previous
//
#include <hip/hip_runtime.h>
#include <hip/hip_bf16.h>

#define N_NODES     65536
#define N_EDGES     524288
#define N_GRAPHS    512
#define G_NODES_N   10000
#define NUM_DIS     2000
#define IN_DIM      128
#define HID         256
#define D_FEAT      512

typedef _Float16 half8 __attribute__((ext_vector_type(8)));
typedef _Float16 half4v __attribute__((ext_vector_type(4)));
typedef float    f32x4 __attribute__((ext_vector_type(4)));

// ---------------------------------------------------------------------------
// 1. Weight convert+transpose: WT[n][k] = (f16) W[k][n].  blockDim.x == K.
// ---------------------------------------------------------------------------
__global__ void wcvt_kernel(const float* __restrict__ W, _Float16* __restrict__ WT,
                            const int N)
{
    const int n = blockIdx.x;
    const int k = threadIdx.x;
    const int K = blockDim.x;
    WT[(size_t)n * K + k] = (_Float16)W[(size_t)k * N + n];
}

// ---------------------------------------------------------------------------
// 2. Projection GEMM (MFMA): proj[base+i] = (f16)( tab[base+i] @ W )  i<M
//    K=512, N=128, BM=128, BN=128, BK=32; fp32 A converted to f16 in staging.
// ---------------------------------------------------------------------------
__global__ __launch_bounds__(256) void proj_mfma_kernel(
    const float* __restrict__ tab, const _Float16* __restrict__ WT,
    _Float16* __restrict__ proj, const int base, const int M)
{
    __shared__ _Float16 Alds[128 * 40];
    __shared__ _Float16 Blds[128 * 40];
    const int bm   = blockIdx.x * 128;
    const int tid  = threadIdx.x;
    const int wave = tid >> 6, lane = tid & 63;
    const int q    = lane >> 4, l16 = lane & 15;
    const int mbase = (wave & 1) * 64, nbase = (wave >> 1) * 64;
    const int r = tid >> 1, s = tid & 1;     // staging: row 0..127, 16-elem segment

    f32x4 acc[4][4] = {};

    for (int kc = 0; kc < 16; ++kc) {
        const int k0 = kc * 32;
        const int arow = min(bm + r, M - 1);
        const float* gA = tab + (size_t)(base + arow) * D_FEAT + k0 + s * 16;
        const _Float16* gB = WT + (size_t)r * D_FEAT + k0 + s * 16;
        const float4 f0 = ((const float4*)gA)[0];
        const float4 f1 = ((const float4*)gA)[1];
        const float4 f2 = ((const float4*)gA)[2];
        const float4 f3 = ((const float4*)gA)[3];
        const half8 hb0 = *(const half8*)gB;
        const half8 hb1 = *(const half8*)(gB + 8);
        half8 h0, h1;
        h0[0]=(_Float16)f0.x; h0[1]=(_Float16)f0.y; h0[2]=(_Float16)f0.z; h0[3]=(_Float16)f0.w;
        h0[4]=(_Float16)f1.x; h0[5]=(_Float16)f1.y; h0[6]=(_Float16)f1.z; h0[7]=(_Float16)f1.w;
        h1[0]=(_Float16)f2.x; h1[1]=(_Float16)f2.y; h1[2]=(_Float16)f2.z; h1[3]=(_Float16)f2.w;
        h1[4]=(_Float16)f3.x; h1[5]=(_Float16)f3.y; h1[6]=(_Float16)f3.z; h1[7]=(_Float16)f3.w;
        __syncthreads();
        *(half8*)&Alds[r * 40 + s * 16]     = h0;
        *(half8*)&Alds[r * 40 + s * 16 + 8] = h1;
        *(half8*)&Blds[r * 40 + s * 16]     = hb0;
        *(half8*)&Blds[r * 40 + s * 16 + 8] = hb1;
        __syncthreads();
        half8 a[4], b[4];
        #pragma unroll
        for (int i = 0; i < 4; ++i)
            a[i] = *(const half8*)&Alds[(mbase + i * 16 + l16) * 40 + q * 8];
        #pragma unroll
        for (int j = 0; j < 4; ++j)
            b[j] = *(const half8*)&Blds[(nbase + j * 16 + l16) * 40 + q * 8];
        #pragma unroll
        for (int i = 0; i < 4; ++i)
            #pragma unroll
            for (int j = 0; j < 4; ++j)
                acc[i][j] = __builtin_amdgcn_mfma_f32_16x16x32_f16(a[i], b[j], acc[i][j], 0, 0, 0);
    }

    #pragma unroll
    for (int j = 0; j < 4; ++j) {
        const int colg = nbase + j * 16 + l16;   // 0..127
        #pragma unroll
        for (int i = 0; i < 4; ++i) {
            #pragma unroll
            for (int rr = 0; rr < 4; ++rr) {
                const int row = bm + mbase + i * 16 + q * 4 + rr;
                if (row < M)
                    proj[(size_t)(base + row) * IN_DIM + colg] = (_Float16)acc[i][j][rr];
            }
        }
    }
}

// ---------------------------------------------------------------------------
// 3. x = concat(z_table[z], proj[node_id])  -> f16  [N_NODES, 256]
// ---------------------------------------------------------------------------
__global__ __launch_bounds__(256) void build_x_kernel(
    const int* __restrict__ z, const int* __restrict__ node_id,
    const float* __restrict__ z_table, const _Float16* __restrict__ proj,
    _Float16* __restrict__ X)
{
    const int t = blockIdx.x * 256 + threadIdx.x;   // < N_NODES*64
    const int node = t >> 6;
    const int q    = t & 63;                        // 4-elem group within row
    half4v h;
    if (q < 32) {
        const float4 v = ((const float4*)(z_table + (size_t)z[node] * IN_DIM))[q];
        h[0] = (_Float16)v.x; h[1] = (_Float16)v.y;
        h[2] = (_Float16)v.z; h[3] = (_Float16)v.w;
    } else {
        h = *(const half4v*)(proj + (size_t)node_id[node] * IN_DIM + (q - 32) * 4);
    }
    *(half4v*)(X + (size_t)node * HID + q * 4) = h;
}

// ---------------------------------------------------------------------------
// 4. CSR build: histogram -> single-block scan -> scatter (src ids per dst)
// ---------------------------------------------------------------------------
__global__ __launch_bounds__(256) void hist_kernel(
    const int* __restrict__ dst, int* __restrict__ cnt)
{
    const int e = blockIdx.x * 256 + threadIdx.x;
    if (e < N_EDGES) atomicAdd(&cnt[dst[e]], 1);
}

__global__ __launch_bounds__(256) void scan_kernel(
    const int* __restrict__ cnt, int* __restrict__ row_ptr)
{
    __shared__ int bufA[256], bufB[256];
    const int t = threadIdx.x;
    const int base = t * 256;
    int s = 0;
    for (int i = 0; i < 256; ++i) s += cnt[base + i];
    bufA[t] = s;
    __syncthreads();
    int* in = bufA; int* out = bufB;
    for (int off = 1; off < 256; off <<= 1) {
        out[t] = in[t] + ((t >= off) ? in[t - off] : 0);
        __syncthreads();
        int* tmp = in; in = out; out = tmp;
    }
    int run = in[t] - s;   // exclusive prefix of this thread's chunk
    for (int i = 0; i < 256; ++i) {
        row_ptr[base + i] = run;
        run += cnt[base + i];
    }
    if (t == 255) row_ptr[N_NODES] = run;
}

__global__ __launch_bounds__(256) void scatter_kernel(
    const int* __restrict__ src, const int* __restrict__ dst,
    const int* __restrict__ row_ptr, int* __restrict__ fill,
    int* __restrict__ col)
{
    const int e = blockIdx.x * 256 + threadIdx.x;
    if (e < N_EDGES) {
        const int d = dst[e];
        const int pos = atomicAdd(&fill[d], 1);
        col[row_ptr[d] + pos] = src[e];
    }
}

// ---------------------------------------------------------------------------
// 5. CSR gather-aggregation: 32 lanes/row (half8 = 16B loads), unroll x2.
//    OUT[d] = [Self[d] +] sum_{s in N(d)} F[s]   [ / max(deg,1) ]
// ---------------------------------------------------------------------------
__global__ __launch_bounds__(256) void csr_agg_kernel(
    const int* __restrict__ row_ptr, const int* __restrict__ col,
    const _Float16* __restrict__ F, const _Float16* __restrict__ Self,
    _Float16* __restrict__ OUT, const int mean_mode)
{
    const int t = blockIdx.x * 256 + threadIdx.x;   // < N_NODES*32
    const int d = t >> 5;
    const int q = t & 31;                           // half8 group within row
    const int beg = row_ptr[d];
    const int end = row_ptr[d + 1];
    float acc[8] = {0.f,0.f,0.f,0.f,0.f,0.f,0.f,0.f};
    if (Self) {
        const half8 sv = *(const half8*)(Self + (size_t)d * HID + q * 8);
        #pragma unroll
        for (int i = 0; i < 8; ++i) acc[i] = (float)sv[i];
    }
    int e = beg;
    for (; e + 2 <= end; e += 2) {
        const int s0 = col[e], s1 = col[e + 1];
        const half8 v0 = *(const half8*)(F + (size_t)s0 * HID + q * 8);
        const half8 v1 = *(const half8*)(F + (size_t)s1 * HID + q * 8);
        #pragma unroll
        for (int i = 0; i < 8; ++i) acc[i] += (float)v0[i] + (float)v1[i];
    }
    if (e < end) {
        const half8 v0 = *(const half8*)(F + (size_t)col[e] * HID + q * 8);
        #pragma unroll
        for (int i = 0; i < 8; ++i) acc[i] += (float)v0[i];
    }
    if (mean_mode) {
        const float rs = 1.0f / fmaxf((float)(end - beg), 1.0f);
        #pragma unroll
        for (int i = 0; i < 8; ++i) acc[i] *= rs;
    }
    half8 o;
    #pragma unroll
    for (int i = 0; i < 8; ++i) o[i] = (_Float16)acc[i];
    *(half8*)(OUT + (size_t)d * HID + q * 8) = o;
}

// ---------------------------------------------------------------------------
// 6. MFMA f16 GEMM: C = act( [A1|A2] @ [B1;B2] + bias )  -> f16
//    BM=128, BN=128, BK=32, 256 threads (4 waves), each wave 64x64.
// ---------------------------------------------------------------------------
__global__ __launch_bounds__(256) void mfma_gemm_kernel(
    const _Float16* __restrict__ A1, const _Float16* __restrict__ A2,
    const _Float16* __restrict__ B1T, const _Float16* __restrict__ B2T,
    const float* __restrict__ bias, _Float16* __restrict__ Ch, const int relu)
{
    __shared__ _Float16 Alds[128 * 40];
    __shared__ _Float16 Blds[128 * 40];
    const int bm   = blockIdx.x * 128;
    const int bn   = blockIdx.y * 128;
    const int tid  = threadIdx.x;
    const int wave = tid >> 6, lane = tid & 63;
    const int q    = lane >> 4, l16 = lane & 15;
    const int mbase = (wave & 1) * 64, nbase = (wave >> 1) * 64;
    const int r = tid >> 1, s = tid & 1;

    f32x4 acc[4][4] = {};
    const int nchunks = A2 ? 16 : 8;

    for (int kc = 0; kc < nchunks; ++kc) {
        const int k0 = (kc & 7) * 32;
        const _Float16* gA = ((kc < 8) ? A1 : A2) + (size_t)(bm + r) * HID + k0 + s * 16;
        const _Float16* gB = ((kc < 8) ? B1T : B2T) + (size_t)(bn + r) * HID + k0 + s * 16;
        const half8 a0 = *(const half8*)gA;
        const half8 a1 = *(const half8*)(gA + 8);
        const half8 b0 = *(const half8*)gB;
        const half8 b1 = *(const half8*)(gB + 8);
        __syncthreads();
        *(half8*)&Alds[r * 40 + s * 16]     = a0;
        *(half8*)&Alds[r * 40 + s * 16 + 8] = a1;
        *(half8*)&Blds[r * 40 + s * 16]     = b0;
        *(half8*)&Blds[r * 40 + s * 16 + 8] = b1;
        __syncthreads();
        half8 a[4], b[4];
        #pragma unroll
        for (int i = 0; i < 4; ++i)
            a[i] = *(const half8*)&Alds[(mbase + i * 16 + l16) * 40 + q * 8];
        #pragma unroll
        for (int j = 0; j < 4; ++j)
            b[j] = *(const half8*)&Blds[(nbase + j * 16 + l16) * 40 + q * 8];
        #pragma unroll
        for (int i = 0; i < 4; ++i)
            #pragma unroll
            for (int j = 0; j < 4; ++j)
                acc[i][j] = __builtin_amdgcn_mfma_f32_16x16x32_f16(a[i], b[j], acc[i][j], 0, 0, 0);
    }

    #pragma unroll
    for (int j = 0; j < 4; ++j) {
        const int colg = bn + nbase + j * 16 + l16;
        const float bv = bias ? bias[colg] : 0.0f;
        #pragma unroll
        for (int i = 0; i < 4; ++i) {
            #pragma unroll
            for (int rr = 0; rr < 4; ++rr) {
                const int rowg = bm + mbase + i * 16 + q * 4 + rr;
                float v = acc[i][j][rr] + bv;
                if (relu) v = fmaxf(v, 0.0f);
                Ch[(size_t)rowg * HID + colg] = (_Float16)v;
            }
        }
    }
}

// ---------------------------------------------------------------------------
// 7. Per-graph max pool (f16 input, fp32 output)
// ---------------------------------------------------------------------------
__global__ __launch_bounds__(256) void pool_kernel(
    const _Float16* __restrict__ H2, const int* __restrict__ gid,
    float* __restrict__ G)
{
    const int g = blockIdx.x;     // 0..511
    const int j = threadIdx.x;    // 0..255
    int lo = 0, hi = N_NODES;
    while (lo < hi) { const int mid = (lo + hi) >> 1; if (gid[mid] < g) lo = mid + 1; else hi = mid; }
    const int start = lo;
    hi = N_NODES;
    while (lo < hi) { const int mid = (lo + hi) >> 1; if (gid[mid] < g + 1) lo = mid + 1; else hi = mid; }
    const int end = lo;
    float m = -INFINITY;
    for (int i = start; i < end; ++i)
        m = fmaxf(m, (float)H2[(size_t)i * HID + j]);
    G[g * HID + j] = (m == -INFINITY) ? 0.0f : m;
}

// ---------------------------------------------------------------------------
// 8. Head: out[g] = relu(G[g] @ lin1 + b1) @ lin2 + b2
// ---------------------------------------------------------------------------
__global__ __launch_bounds__(256) void head_kernel(
    const float* __restrict__ G, const float* __restrict__ W1,
    const float* __restrict__ b1, const float* __restrict__ W2,
    const float* __restrict__ b2, float* __restrict__ out)
{
    const int g = blockIdx.x;
    const int j = threadIdx.x;    // 0..255
    __shared__ float row[HID];
    __shared__ float red[HID];
    row[j] = G[g * HID + j];
    __syncthreads();
    float acc = b1[j];
    for (int k = 0; k < HID; ++k)
        acc = fmaf(row[k], W1[k * HID + j], acc);
    acc = fmaxf(acc, 0.f);
    red[j] = acc * W2[j];
    __syncthreads();
    for (int s = 128; s > 0; s >>= 1) {
        if (j < s) red[j] += red[j + s];
        __syncthreads();
    }
    if (j == 0) out[g] = red[0] + b2[0];
}

// ---------------------------------------------------------------------------
extern "C" void kernel_launch(void* const* d_in, const int* in_sizes, int n_in,
                              void* d_out, int out_size, void* d_ws, size_t ws_size,
                              hipStream_t stream)
{
    const int*   z         = (const int*)d_in[0];
    const int*   node_id   = (const int*)d_in[1];
    const int*   src       = (const int*)d_in[2];
    const int*   dst       = (const int*)d_in[3];
    const int*   graph_ids = (const int*)d_in[4];
    const float* z_table   = (const float*)d_in[5];
    const float* d_feat    = (const float*)d_in[6];
    const float* c_feat    = (const float*)d_in[7];
    const float* Wd        = (const float*)d_in[8];
    const float* Wc        = (const float*)d_in[9];
    const float* gin_W1    = (const float*)d_in[10];
    const float* gin_b1    = (const float*)d_in[11];
    const float* gin_W2    = (const float*)d_in[12];
    const float* gin_b2    = (const float*)d_in[13];
    const float* sage_Wself  = (const float*)d_in[14];
    const float* sage_Wneigh = (const float*)d_in[15];
    const float* sage_b    = (const float*)d_in[16];
    const float* lin1_W    = (const float*)d_in[17];
    const float* lin1_b    = (const float*)d_in[18];
    const float* lin2_W    = (const float*)d_in[19];
    const float* lin2_b    = (const float*)d_in[20];
    float* out = (float*)d_out;

    // ---- workspace carve-up (all f16 node-feature buffers) ----
    const size_t NH = (size_t)N_NODES * HID;        // 16,777,216 elements
    char* wsb = (char*)d_ws;
    _Float16* bufA = (_Float16*)wsb;                     wsb += NH * 2;  // Xh -> Hh
    _Float16* AGGh = (_Float16*)wsb;                     wsb += NH * 2;  // both aggs
    _Float16* H1h  = (_Float16*)wsb;                     wsb += NH * 2;  // H1 -> H2
    _Float16* projh= (_Float16*)wsb;                     wsb += (size_t)G_NODES_N * IN_DIM * 2;
    _Float16* W1T  = (_Float16*)wsb;                     wsb += HID * HID * 2;
    _Float16* W2T  = (_Float16*)wsb;                     wsb += HID * HID * 2;
    _Float16* WsT  = (_Float16*)wsb;                     wsb += HID * HID * 2;
    _Float16* WnT  = (_Float16*)wsb;                     wsb += HID * HID * 2;
    _Float16* WdT  = (_Float16*)wsb;                     wsb += D_FEAT * IN_DIM * 2;
    _Float16* WcT  = (_Float16*)wsb;                     wsb += D_FEAT * IN_DIM * 2;
    float*    G    = (float*)wsb;                        wsb += (size_t)N_GRAPHS * HID * 4;
    int* row_ptr   = (int*)wsb;                          wsb += (N_NODES + 4) * 4;
    int* cnt       = (int*)wsb;                          wsb += N_NODES * 4;
    int* col       = (int*)wsb;                          wsb += N_EDGES * 4;

    _Float16* Xh  = bufA;
    _Float16* Hh  = bufA;   // reuse after X dead
    _Float16* H2h = H1h;    // reuse after H1 dead

    // ---- CSR build (shared by both aggregations) ----
    hipMemsetAsync(cnt, 0, N_NODES * sizeof(int), stream);
    hist_kernel<<<N_EDGES / 256, 256, 0, stream>>>(dst, cnt);
    scan_kernel<<<1, 256, 0, stream>>>(cnt, row_ptr);
    hipMemsetAsync(cnt, 0, N_NODES * sizeof(int), stream);
    scatter_kernel<<<N_EDGES / 256, 256, 0, stream>>>(src, dst, row_ptr, cnt, col);

    // ---- weights -> f16 transposed ----
    wcvt_kernel<<<HID, HID, 0, stream>>>(gin_W1, W1T, HID);
    wcvt_kernel<<<HID, HID, 0, stream>>>(gin_W2, W2T, HID);
    wcvt_kernel<<<HID, HID, 0, stream>>>(sage_Wself, WsT, HID);
    wcvt_kernel<<<HID, HID, 0, stream>>>(sage_Wneigh, WnT, HID);
    wcvt_kernel<<<IN_DIM, D_FEAT, 0, stream>>>(Wd, WdT, IN_DIM);
    wcvt_kernel<<<IN_DIM, D_FEAT, 0, stream>>>(Wc, WcT, IN_DIM);

    // ---- projection table via MFMA: rows 0..2000 @Wd, 2001..9999 @Wc ----
    proj_mfma_kernel<<<(NUM_DIS + 1 + 127) / 128, 256, 0, stream>>>(
        d_feat, WdT, projh, 0, NUM_DIS + 1);
    proj_mfma_kernel<<<(G_NODES_N - NUM_DIS - 1 + 127) / 128, 256, 0, stream>>>(
        c_feat, WcT, projh, NUM_DIS + 1, G_NODES_N - NUM_DIS - 1);

    // ---- build x ----
    build_x_kernel<<<(N_NODES * 64) / 256, 256, 0, stream>>>(z, node_id, z_table, projh, Xh);

    // ---- GIN aggregation: AGG = X + sum_neigh(X) ----
    csr_agg_kernel<<<(N_NODES * 32) / 256, 256, 0, stream>>>(row_ptr, col, Xh, Xh, AGGh, 0);

    // ---- GIN MLP: H1 = relu(AGG@W1+b1); H = H1@W2+b2 ----
    dim3 ggrid(N_NODES / 128, HID / 128);
    mfma_gemm_kernel<<<ggrid, 256, 0, stream>>>(AGGh, nullptr, W1T, nullptr, gin_b1, H1h, 1);
    mfma_gemm_kernel<<<ggrid, 256, 0, stream>>>(H1h, nullptr, W2T, nullptr, gin_b2, Hh, 0);

    // ---- SAGE mean aggregation: AGG = mean_neigh(H) ----
    csr_agg_kernel<<<(N_NODES * 32) / 256, 256, 0, stream>>>(row_ptr, col, Hh, nullptr, AGGh, 1);

    // ---- SAGE fused: H2 = H@Wself + AGG@Wneigh + b  (K=512) ----
    mfma_gemm_kernel<<<ggrid, 256, 0, stream>>>(Hh, AGGh, WsT, WnT, sage_b, H2h, 0);

    // ---- per-graph max pool ----
    pool_kernel<<<N_GRAPHS, 256, 0, stream>>>(H2h, graph_ids, G);

    // ---- head ----
    head_kernel<<<N_GRAPHS, 256, 0, stream>>>(G, lin1_W, lin1_b, lin2_W, lin2_b, out);
}

// Round 6
// 426.970 us; speedup vs baseline: 9.9807x; 1.1434x over previous
//
#include <hip/hip_runtime.h>
#include <hip/hip_bf16.h>

#define N_NODES     65536
#define N_EDGES     524288
#define N_GRAPHS    512
#define G_NODES_N   10000
#define NUM_DIS     2000
#define IN_DIM      128
#define HID         256
#define D_FEAT      512

typedef _Float16 half8 __attribute__((ext_vector_type(8)));
typedef _Float16 half4v __attribute__((ext_vector_type(4)));
typedef float    f32x4 __attribute__((ext_vector_type(4)));

// ---------------------------------------------------------------------------
// 1. All six weight transposes in ONE dispatch.
//    blocks 0..1023: 256x256 mats (W1,W2,Ws,Wn); 1024..1279: 512x128 (Wd,Wc)
// ---------------------------------------------------------------------------
__global__ __launch_bounds__(256) void wcvt_all_kernel(
    const float* __restrict__ W1, const float* __restrict__ W2,
    const float* __restrict__ Ws, const float* __restrict__ Wn,
    const float* __restrict__ Wd, const float* __restrict__ Wc,
    _Float16* __restrict__ W1T, _Float16* __restrict__ W2T,
    _Float16* __restrict__ WsT, _Float16* __restrict__ WnT,
    _Float16* __restrict__ WdT, _Float16* __restrict__ WcT)
{
    int b = blockIdx.x;
    const float* W; _Float16* T; int N, K, n;
    if (b < 1024) {
        const int m = b >> 8; n = b & 255; N = HID; K = HID;
        W = (m == 0) ? W1 : (m == 1) ? W2 : (m == 2) ? Ws : Wn;
        T = (m == 0) ? W1T : (m == 1) ? W2T : (m == 2) ? WsT : WnT;
    } else {
        b -= 1024; const int m = b >> 7; n = b & 127; N = IN_DIM; K = D_FEAT;
        W = (m == 0) ? Wd : Wc;
        T = (m == 0) ? WdT : WcT;
    }
    for (int k = threadIdx.x; k < K; k += 256)
        T[(size_t)n * K + k] = (_Float16)W[(size_t)k * N + n];
}

// ---------------------------------------------------------------------------
// 2. Projection GEMM (MFMA), BOTH segments in one dispatch.
//    blocks 0..15: rows 0..2000 of d_feat @ Wd; 16..78: rows 2001..9999 @ Wc
// ---------------------------------------------------------------------------
__global__ __launch_bounds__(256) void proj_mfma_kernel(
    const float* __restrict__ dtab, const float* __restrict__ ctab,
    const _Float16* __restrict__ WdT, const _Float16* __restrict__ WcT,
    _Float16* __restrict__ proj)
{
    __shared__ _Float16 Alds[128 * 40];
    __shared__ _Float16 Blds[128 * 40];
    const int blk = blockIdx.x;
    const float* tab; const _Float16* WT; int base, M, bm;
    if (blk < 16) { tab = dtab; WT = WdT; base = 0;           M = NUM_DIS + 1;             bm = blk * 128; }
    else          { tab = ctab; WT = WcT; base = NUM_DIS + 1; M = G_NODES_N - NUM_DIS - 1; bm = (blk - 16) * 128; }
    const int tid  = threadIdx.x;
    const int wave = tid >> 6, lane = tid & 63;
    const int q    = lane >> 4, l16 = lane & 15;
    const int mbase = (wave & 1) * 64, nbase = (wave >> 1) * 64;
    const int r = tid >> 1, s = tid & 1;

    f32x4 acc[4][4] = {};

    for (int kc = 0; kc < 16; ++kc) {
        const int k0 = kc * 32;
        const int arow = min(bm + r, M - 1);
        const float* gA = tab + (size_t)(base + arow) * D_FEAT + k0 + s * 16;
        const _Float16* gB = WT + (size_t)r * D_FEAT + k0 + s * 16;
        const float4 f0 = ((const float4*)gA)[0];
        const float4 f1 = ((const float4*)gA)[1];
        const float4 f2 = ((const float4*)gA)[2];
        const float4 f3 = ((const float4*)gA)[3];
        const half8 hb0 = *(const half8*)gB;
        const half8 hb1 = *(const half8*)(gB + 8);
        half8 h0, h1;
        h0[0]=(_Float16)f0.x; h0[1]=(_Float16)f0.y; h0[2]=(_Float16)f0.z; h0[3]=(_Float16)f0.w;
        h0[4]=(_Float16)f1.x; h0[5]=(_Float16)f1.y; h0[6]=(_Float16)f1.z; h0[7]=(_Float16)f1.w;
        h1[0]=(_Float16)f2.x; h1[1]=(_Float16)f2.y; h1[2]=(_Float16)f2.z; h1[3]=(_Float16)f2.w;
        h1[4]=(_Float16)f3.x; h1[5]=(_Float16)f3.y; h1[6]=(_Float16)f3.z; h1[7]=(_Float16)f3.w;
        __syncthreads();
        *(half8*)&Alds[r * 40 + s * 16]     = h0;
        *(half8*)&Alds[r * 40 + s * 16 + 8] = h1;
        *(half8*)&Blds[r * 40 + s * 16]     = hb0;
        *(half8*)&Blds[r * 40 + s * 16 + 8] = hb1;
        __syncthreads();
        half8 a[4], b[4];
        #pragma unroll
        for (int i = 0; i < 4; ++i)
            a[i] = *(const half8*)&Alds[(mbase + i * 16 + l16) * 40 + q * 8];
        #pragma unroll
        for (int j = 0; j < 4; ++j)
            b[j] = *(const half8*)&Blds[(nbase + j * 16 + l16) * 40 + q * 8];
        #pragma unroll
        for (int i = 0; i < 4; ++i)
            #pragma unroll
            for (int j = 0; j < 4; ++j)
                acc[i][j] = __builtin_amdgcn_mfma_f32_16x16x32_f16(a[i], b[j], acc[i][j], 0, 0, 0);
    }

    #pragma unroll
    for (int j = 0; j < 4; ++j) {
        const int colg = nbase + j * 16 + l16;   // 0..127
        #pragma unroll
        for (int i = 0; i < 4; ++i) {
            #pragma unroll
            for (int rr = 0; rr < 4; ++rr) {
                const int row = bm + mbase + i * 16 + q * 4 + rr;
                if (row < M)
                    proj[(size_t)(base + row) * IN_DIM + colg] = (_Float16)acc[i][j][rr];
            }
        }
    }
}

// ---------------------------------------------------------------------------
// 3. x = concat(z_table[z], proj[node_id])  -> f16  [N_NODES, 256]
// ---------------------------------------------------------------------------
__global__ __launch_bounds__(256) void build_x_kernel(
    const int* __restrict__ z, const int* __restrict__ node_id,
    const float* __restrict__ z_table, const _Float16* __restrict__ proj,
    _Float16* __restrict__ X)
{
    const int t = blockIdx.x * 256 + threadIdx.x;   // < N_NODES*64
    const int node = t >> 6;
    const int q    = t & 63;
    half4v h;
    if (q < 32) {
        const float4 v = ((const float4*)(z_table + (size_t)z[node] * IN_DIM))[q];
        h[0] = (_Float16)v.x; h[1] = (_Float16)v.y;
        h[2] = (_Float16)v.z; h[3] = (_Float16)v.w;
    } else {
        h = *(const half4v*)(proj + (size_t)node_id[node] * IN_DIM + (q - 32) * 4);
    }
    *(half4v*)(X + (size_t)node * HID + q * 4) = h;
}

// ---------------------------------------------------------------------------
// 4. CSR build: hist -> 3-phase hierarchical scan (coalesced) -> scatter
// ---------------------------------------------------------------------------
__global__ __launch_bounds__(256) void hist_kernel(
    const int* __restrict__ dst, int* __restrict__ cnt)
{
    const int e = blockIdx.x * 256 + threadIdx.x;
    if (e < N_EDGES) atomicAdd(&cnt[dst[e]], 1);
}

// Phase A: 64 blocks, each sums a 1024-int segment of cnt.
__global__ __launch_bounds__(256) void seg_sum_kernel(
    const int* __restrict__ cnt, int* __restrict__ seg)
{
    __shared__ int red[256];
    const int t = threadIdx.x;
    const int4 c = *(const int4*)(cnt + blockIdx.x * 1024 + t * 4);
    red[t] = c.x + c.y + c.z + c.w;
    __syncthreads();
    for (int s = 128; s > 0; s >>= 1) {
        if (t < s) red[t] += red[t + s];
        __syncthreads();
    }
    if (t == 0) seg[blockIdx.x] = red[0];
}

// Phase B: one wave scans the 64 segment sums.
__global__ __launch_bounds__(64) void seg_scan_kernel(
    const int* __restrict__ seg, int* __restrict__ segoff,
    int* __restrict__ total_out)
{
    __shared__ int a[64], b[64];
    const int t = threadIdx.x;
    const int v = seg[t];
    a[t] = v;
    __syncthreads();
    int* in = a; int* out = b;
    for (int off = 1; off < 64; off <<= 1) {
        out[t] = in[t] + ((t >= off) ? in[t - off] : 0);
        __syncthreads();
        int* tmp = in; in = out; out = tmp;
    }
    segoff[t] = in[t] - v;          // exclusive
    if (t == 63) total_out[0] = in[63];
}

// Phase C: 64 blocks; coalesced int4 local exclusive scan + seg offset.
// Writes row_ptr AND fill (scatter's atomic cursor) in one pass.
__global__ __launch_bounds__(256) void local_scan_kernel(
    const int* __restrict__ cnt, const int* __restrict__ segoff,
    int* __restrict__ row_ptr, int* __restrict__ fill)
{
    __shared__ int a[256], b[256];
    const int t = threadIdx.x;
    const int base = blockIdx.x * 1024 + t * 4;
    const int4 c = *(const int4*)(cnt + base);
    const int s = c.x + c.y + c.z + c.w;
    a[t] = s;
    __syncthreads();
    int* in = a; int* out = b;
    for (int off = 1; off < 256; off <<= 1) {
        out[t] = in[t] + ((t >= off) ? in[t - off] : 0);
        __syncthreads();
        int* tmp = in; in = out; out = tmp;
    }
    const int run = in[t] - s + segoff[blockIdx.x];
    int4 r;
    r.x = run; r.y = run + c.x; r.z = r.y + c.y; r.w = r.z + c.z;
    *(int4*)(row_ptr + base) = r;
    *(int4*)(fill + base) = r;
}

__global__ __launch_bounds__(256) void scatter_kernel(
    const int* __restrict__ src, const int* __restrict__ dst,
    int* __restrict__ fill, int* __restrict__ col)
{
    const int e = blockIdx.x * 256 + threadIdx.x;
    if (e < N_EDGES) {
        const int pos = atomicAdd(&fill[dst[e]], 1);   // fill pre-seeded = row_ptr
        col[pos] = src[e];
    }
}

// ---------------------------------------------------------------------------
// 5. CSR gather-aggregation: 32 lanes/row (16B loads), unroll x4.
//    OUT[d] = [Self[d] +] sum_{s in N(d)} F[s]   [ / max(deg,1) ]
// ---------------------------------------------------------------------------
__global__ __launch_bounds__(256) void csr_agg_kernel(
    const int* __restrict__ row_ptr, const int* __restrict__ col,
    const _Float16* __restrict__ F, const _Float16* __restrict__ Self,
    _Float16* __restrict__ OUT, const int mean_mode)
{
    const int t = blockIdx.x * 256 + threadIdx.x;   // < N_NODES*32
    const int d = t >> 5;
    const int q = t & 31;
    const int beg = row_ptr[d];
    const int end = row_ptr[d + 1];
    float acc[8] = {0.f,0.f,0.f,0.f,0.f,0.f,0.f,0.f};
    if (Self) {
        const half8 sv = *(const half8*)(Self + (size_t)d * HID + q * 8);
        #pragma unroll
        for (int i = 0; i < 8; ++i) acc[i] = (float)sv[i];
    }
    int e = beg;
    for (; e + 4 <= end; e += 4) {
        const int s0 = col[e],     s1 = col[e + 1];
        const int s2 = col[e + 2], s3 = col[e + 3];
        const half8 v0 = *(const half8*)(F + (size_t)s0 * HID + q * 8);
        const half8 v1 = *(const half8*)(F + (size_t)s1 * HID + q * 8);
        const half8 v2 = *(const half8*)(F + (size_t)s2 * HID + q * 8);
        const half8 v3 = *(const half8*)(F + (size_t)s3 * HID + q * 8);
        #pragma unroll
        for (int i = 0; i < 8; ++i)
            acc[i] += ((float)v0[i] + (float)v1[i]) + ((float)v2[i] + (float)v3[i]);
    }
    for (; e < end; ++e) {
        const half8 v0 = *(const half8*)(F + (size_t)col[e] * HID + q * 8);
        #pragma unroll
        for (int i = 0; i < 8; ++i) acc[i] += (float)v0[i];
    }
    if (mean_mode) {
        const float rs = 1.0f / fmaxf((float)(end - beg), 1.0f);
        #pragma unroll
        for (int i = 0; i < 8; ++i) acc[i] *= rs;
    }
    half8 o;
    #pragma unroll
    for (int i = 0; i < 8; ++i) o[i] = (_Float16)acc[i];
    *(half8*)(OUT + (size_t)d * HID + q * 8) = o;
}

// ---------------------------------------------------------------------------
// 6. MFMA f16 GEMM: C = act( [A1|A2] @ [B1;B2] + bias )  -> f16
// ---------------------------------------------------------------------------
__global__ __launch_bounds__(256) void mfma_gemm_kernel(
    const _Float16* __restrict__ A1, const _Float16* __restrict__ A2,
    const _Float16* __restrict__ B1T, const _Float16* __restrict__ B2T,
    const float* __restrict__ bias, _Float16* __restrict__ Ch, const int relu)
{
    __shared__ _Float16 Alds[128 * 40];
    __shared__ _Float16 Blds[128 * 40];
    const int bm   = blockIdx.x * 128;
    const int bn   = blockIdx.y * 128;
    const int tid  = threadIdx.x;
    const int wave = tid >> 6, lane = tid & 63;
    const int q    = lane >> 4, l16 = lane & 15;
    const int mbase = (wave & 1) * 64, nbase = (wave >> 1) * 64;
    const int r = tid >> 1, s = tid & 1;

    f32x4 acc[4][4] = {};
    const int nchunks = A2 ? 16 : 8;

    for (int kc = 0; kc < nchunks; ++kc) {
        const int k0 = (kc & 7) * 32;
        const _Float16* gA = ((kc < 8) ? A1 : A2) + (size_t)(bm + r) * HID + k0 + s * 16;
        const _Float16* gB = ((kc < 8) ? B1T : B2T) + (size_t)(bn + r) * HID + k0 + s * 16;
        const half8 a0 = *(const half8*)gA;
        const half8 a1 = *(const half8*)(gA + 8);
        const half8 b0 = *(const half8*)gB;
        const half8 b1 = *(const half8*)(gB + 8);
        __syncthreads();
        *(half8*)&Alds[r * 40 + s * 16]     = a0;
        *(half8*)&Alds[r * 40 + s * 16 + 8] = a1;
        *(half8*)&Blds[r * 40 + s * 16]     = b0;
        *(half8*)&Blds[r * 40 + s * 16 + 8] = b1;
        __syncthreads();
        half8 a[4], b[4];
        #pragma unroll
        for (int i = 0; i < 4; ++i)
            a[i] = *(const half8*)&Alds[(mbase + i * 16 + l16) * 40 + q * 8];
        #pragma unroll
        for (int j = 0; j < 4; ++j)
            b[j] = *(const half8*)&Blds[(nbase + j * 16 + l16) * 40 + q * 8];
        #pragma unroll
        for (int i = 0; i < 4; ++i)
            #pragma unroll
            for (int j = 0; j < 4; ++j)
                acc[i][j] = __builtin_amdgcn_mfma_f32_16x16x32_f16(a[i], b[j], acc[i][j], 0, 0, 0);
    }

    #pragma unroll
    for (int j = 0; j < 4; ++j) {
        const int colg = bn + nbase + j * 16 + l16;
        const float bv = bias ? bias[colg] : 0.0f;
        #pragma unroll
        for (int i = 0; i < 4; ++i) {
            #pragma unroll
            for (int rr = 0; rr < 4; ++rr) {
                const int rowg = bm + mbase + i * 16 + q * 4 + rr;
                float v = acc[i][j][rr] + bv;
                if (relu) v = fmaxf(v, 0.0f);
                Ch[(size_t)rowg * HID + colg] = (_Float16)v;
            }
        }
    }
}

// ---------------------------------------------------------------------------
// 7. Fused per-graph max pool + head MLP: one block per graph.
//    out[g] = relu(maxpool(H2[range g]) @ lin1 + b1) @ lin2 + b2
// ---------------------------------------------------------------------------
__global__ __launch_bounds__(256) void pool_head_kernel(
    const _Float16* __restrict__ H2, const int* __restrict__ gid,
    const float* __restrict__ W1, const float* __restrict__ b1,
    const float* __restrict__ W2, const float* __restrict__ b2,
    float* __restrict__ out)
{
    const int g = blockIdx.x;     // 0..511
    const int j = threadIdx.x;    // 0..255
    __shared__ float row[HID];
    __shared__ float red[HID];
    int lo = 0, hi = N_NODES;
    while (lo < hi) { const int mid = (lo + hi) >> 1; if (gid[mid] < g) lo = mid + 1; else hi = mid; }
    const int start = lo;
    hi = N_NODES;
    while (lo < hi) { const int mid = (lo + hi) >> 1; if (gid[mid] < g + 1) lo = mid + 1; else hi = mid; }
    const int end = lo;
    float m = -INFINITY;
    for (int i = start; i < end; ++i)
        m = fmaxf(m, (float)H2[(size_t)i * HID + j]);
    row[j] = (m == -INFINITY) ? 0.0f : m;
    __syncthreads();
    float acc = b1[j];
    for (int k = 0; k < HID; ++k)
        acc = fmaf(row[k], W1[k * HID + j], acc);
    acc = fmaxf(acc, 0.f);
    red[j] = acc * W2[j];
    __syncthreads();
    for (int s = 128; s > 0; s >>= 1) {
        if (j < s) red[j] += red[j + s];
        __syncthreads();
    }
    if (j == 0) out[g] = red[0] + b2[0];
}

// ---------------------------------------------------------------------------
extern "C" void kernel_launch(void* const* d_in, const int* in_sizes, int n_in,
                              void* d_out, int out_size, void* d_ws, size_t ws_size,
                              hipStream_t stream)
{
    const int*   z         = (const int*)d_in[0];
    const int*   node_id   = (const int*)d_in[1];
    const int*   src       = (const int*)d_in[2];
    const int*   dst       = (const int*)d_in[3];
    const int*   graph_ids = (const int*)d_in[4];
    const float* z_table   = (const float*)d_in[5];
    const float* d_feat    = (const float*)d_in[6];
    const float* c_feat    = (const float*)d_in[7];
    const float* Wd        = (const float*)d_in[8];
    const float* Wc        = (const float*)d_in[9];
    const float* gin_W1    = (const float*)d_in[10];
    const float* gin_b1    = (const float*)d_in[11];
    const float* gin_W2    = (const float*)d_in[12];
    const float* gin_b2    = (const float*)d_in[13];
    const float* sage_Wself  = (const float*)d_in[14];
    const float* sage_Wneigh = (const float*)d_in[15];
    const float* sage_b    = (const float*)d_in[16];
    const float* lin1_W    = (const float*)d_in[17];
    const float* lin1_b    = (const float*)d_in[18];
    const float* lin2_W    = (const float*)d_in[19];
    const float* lin2_b    = (const float*)d_in[20];
    float* out = (float*)d_out;

    // ---- workspace carve-up (16B-aligned chunks) ----
    const size_t NH = (size_t)N_NODES * HID;        // 16,777,216 elements
    char* wsb = (char*)d_ws;
    _Float16* bufA = (_Float16*)wsb;                     wsb += NH * 2;  // Xh -> Hh
    _Float16* AGGh = (_Float16*)wsb;                     wsb += NH * 2;  // both aggs
    _Float16* H1h  = (_Float16*)wsb;                     wsb += NH * 2;  // H1 -> H2
    _Float16* projh= (_Float16*)wsb;                     wsb += (size_t)G_NODES_N * IN_DIM * 2;
    _Float16* W1T  = (_Float16*)wsb;                     wsb += HID * HID * 2;
    _Float16* W2T  = (_Float16*)wsb;                     wsb += HID * HID * 2;
    _Float16* WsT  = (_Float16*)wsb;                     wsb += HID * HID * 2;
    _Float16* WnT  = (_Float16*)wsb;                     wsb += HID * HID * 2;
    _Float16* WdT  = (_Float16*)wsb;                     wsb += D_FEAT * IN_DIM * 2;
    _Float16* WcT  = (_Float16*)wsb;                     wsb += D_FEAT * IN_DIM * 2;
    int* row_ptr   = (int*)wsb;                          wsb += (N_NODES + 4) * 4;
    int* cnt       = (int*)wsb;                          wsb += N_NODES * 4;
    int* fill      = (int*)wsb;                          wsb += N_NODES * 4;
    int* col       = (int*)wsb;                          wsb += N_EDGES * 4;
    int* seg       = (int*)wsb;                          wsb += 64 * 4;
    int* segoff    = (int*)wsb;                          wsb += 64 * 4;

    _Float16* Xh  = bufA;
    _Float16* Hh  = bufA;   // reuse after X dead
    _Float16* H2h = H1h;    // reuse after H1 dead

    // ---- CSR build ----
    hipMemsetAsync(cnt, 0, N_NODES * sizeof(int), stream);
    hist_kernel<<<N_EDGES / 256, 256, 0, stream>>>(dst, cnt);
    seg_sum_kernel<<<64, 256, 0, stream>>>(cnt, seg);
    seg_scan_kernel<<<1, 64, 0, stream>>>(seg, segoff, &row_ptr[N_NODES]);
    local_scan_kernel<<<64, 256, 0, stream>>>(cnt, segoff, row_ptr, fill);
    scatter_kernel<<<N_EDGES / 256, 256, 0, stream>>>(src, dst, fill, col);

    // ---- weights -> f16 transposed (one dispatch) ----
    wcvt_all_kernel<<<1280, 256, 0, stream>>>(gin_W1, gin_W2, sage_Wself, sage_Wneigh,
                                              Wd, Wc, W1T, W2T, WsT, WnT, WdT, WcT);

    // ---- projection table via MFMA (both segments, one dispatch) ----
    proj_mfma_kernel<<<16 + 63, 256, 0, stream>>>(d_feat, c_feat, WdT, WcT, projh);

    // ---- build x ----
    build_x_kernel<<<(N_NODES * 64) / 256, 256, 0, stream>>>(z, node_id, z_table, projh, Xh);

    // ---- GIN aggregation: AGG = X + sum_neigh(X) ----
    csr_agg_kernel<<<(N_NODES * 32) / 256, 256, 0, stream>>>(row_ptr, col, Xh, Xh, AGGh, 0);

    // ---- GIN MLP: H1 = relu(AGG@W1+b1); H = H1@W2+b2 ----
    dim3 ggrid(N_NODES / 128, HID / 128);
    mfma_gemm_kernel<<<ggrid, 256, 0, stream>>>(AGGh, nullptr, W1T, nullptr, gin_b1, H1h, 1);
    mfma_gemm_kernel<<<ggrid, 256, 0, stream>>>(H1h, nullptr, W2T, nullptr, gin_b2, Hh, 0);

    // ---- SAGE mean aggregation: AGG = mean_neigh(H) ----
    csr_agg_kernel<<<(N_NODES * 32) / 256, 256, 0, stream>>>(row_ptr, col, Hh, nullptr, AGGh, 1);

    // ---- SAGE fused: H2 = H@Wself + AGG@Wneigh + b  (K=512) ----
    mfma_gemm_kernel<<<ggrid, 256, 0, stream>>>(Hh, AGGh, WsT, WnT, sage_b, H2h, 0);

    // ---- fused per-graph max pool + head ----
    pool_head_kernel<<<N_GRAPHS, 256, 0, stream>>>(H2h, graph_ids, lin1_W, lin1_b,
                                                   lin2_W, lin2_b, out);
}